// Round 8
// baseline (61.530 us; speedup 1.0000x reference)
//
#include <hip/hip_runtime.h>
#include <hip/hip_fp16.h>

#define BATCH  16384
#define NFEAT  50
#define NF4    13            // features padded to 52 = 13*4
#define DIM    128
#define NROWS  2000
#define SLICES 8
#define SD     16            // dims per slice
#define ROW_DW 12            // 8 data dwords (16 f16) + 4 pad; 48B stride, 16B-aligned
#define LDS3_BYTES (NROWS * ROW_DW * 4)   // 96000 B

// workspace layout (bytes)
#define WSA_OFF 0u                         // f16 sliced tables [2][8][2000][16]   (1,024,000)
#define WSB_OFF (1u<<20)                   // PT4 [2][13][16384] uint4             (6,815,744)
#define WSD_OFF (8u*1024u*1024u)           // delta f16 [2][16384][128]            (8,388,608)
#define WS_NEEDED (16u*1024u*1024u)        // 16 MB total

// ---- K1: slice + f32->f16 convert both feature tables -----------------------
// 32000 8-dim chunks per table (2000 rows x 16 chunks).
// out f16 index: ((t*8+s)*2000 + r)*16 + hlf*8
__global__ __launch_bounds__(256) void k1_slice_tables(
    const float* __restrict__ ufe,
    const float* __restrict__ ife,
    ushort*      __restrict__ wsa)
{
    const int u = blockIdx.x * 256 + threadIdx.x;   // 0..63999
    const int t   = (u >= 32000) ? 1 : 0;           // FIX: split at 32000, not 32768
    const int rem = u - t * 32000;                  // 0..31999
    const int r = rem >> 4;                         // row 0..1999
    const int k = rem & 15;                         // 8-dim chunk within row
    const float* src = (t ? ife : ufe) + (size_t)r * DIM + k * 8;
    const float4 a = *reinterpret_cast<const float4*>(src);
    const float4 b = *reinterpret_cast<const float4*>(src + 4);
    __half2 hh[4];
    hh[0] = __floats2half2_rn(a.x, a.y);
    hh[1] = __floats2half2_rn(a.z, a.w);
    hh[2] = __floats2half2_rn(b.x, b.y);
    hh[3] = __floats2half2_rn(b.z, b.w);
    const int s = k >> 1, hlf = k & 1;
    const size_t fidx = ((size_t)(t * 8 + s) * NROWS + r) * SD + hlf * 8;
    *reinterpret_cast<uint4*>(wsa + fidx) = *reinterpret_cast<uint4*>(hh);
}

// ---- K2: transpose + pack (idx | f16val) into PT4 [2][13][16384] uint4 ------
__global__ __launch_bounds__(256) void k2_pack_transpose(
    const int*   __restrict__ ufi,
    const float* __restrict__ ufv,
    const int*   __restrict__ ifi,
    const float* __restrict__ ifv,
    uint*        __restrict__ wsb)   // as dwords; uint4-granular stores
{
    __shared__ uint pk[256][53];     // 53-dword stride (odd) for write-phase reads

    const int t    = blockIdx.x & 1;
    const int tile = blockIdx.x >> 1;          // 0..63
    const int e0   = tile * 256;
    const int tid  = threadIdx.x;

    const int*   __restrict__ fi = t ? ifi : ufi;
    const float* __restrict__ fv = t ? ifv : ufv;

    pk[tid][50] = 0u;
    pk[tid][51] = 0u;

    #pragma unroll
    for (int jj = 0; jj < 50; ++jj) {
        const int flat = jj * 256 + tid;       // 0..12799, coalesced
        const int el = flat / 50, f = flat % 50;
        const uint  idx = (uint)fi[(size_t)e0 * NFEAT + flat];
        const float val = fv[(size_t)e0 * NFEAT + flat];
        const uint  vh  = (uint)__half_as_ushort(__float2half(val));
        pk[el][f] = (idx & 0xffffu) | (vh << 16);
    }
    __syncthreads();

    #pragma unroll
    for (int f4 = 0; f4 < NF4; ++f4) {
        uint4 o;
        o.x = pk[tid][f4 * 4 + 0];
        o.y = pk[tid][f4 * 4 + 1];
        o.z = pk[tid][f4 * 4 + 2];
        o.w = pk[tid][f4 * 4 + 3];
        reinterpret_cast<uint4*>(wsb)[(size_t)(t * NF4 + f4) * BATCH + e0 + tid] = o;
    }
}

// ---- K3: LDS-staged slice gather -> delta f16 -------------------------------
// grid 256 = (2 tables x 8 slices) x 16 copies; 1024 threads; 96 KB dynamic LDS.
__global__ __launch_bounds__(1024) void k3_delta(
    const ushort* __restrict__ wsa,
    const uint*   __restrict__ wsb,
    ushort*       __restrict__ wsd)
{
    extern __shared__ uint ldsu[];

    const int task = blockIdx.x >> 4;    // 0..15
    const int copy = blockIdx.x & 15;
    const int t = task >> 3;
    const int s = task & 7;
    const int tid = threadIdx.x;

    // ---- stage this (table, slice): 2000 rows x 32B -> stride-48B LDS rows ----
    {
        const uint4* src = reinterpret_cast<const uint4*>(
            wsa + (size_t)(t * 8 + s) * NROWS * SD);   // 2 uint4 chunks per row
        #pragma unroll
        for (int p = 0; p < 4; ++p) {
            const int c = p * 1024 + tid;              // 0..4095, need 4000
            if (c < NROWS * 2) {
                const int r = c >> 1, h = c & 1;
                *reinterpret_cast<uint4*>(&ldsu[r * ROW_DW + h * 4]) = src[c];
            }
        }
    }
    __syncthreads();

    const int lane = tid & 63;
    const int w    = tid >> 6;          // wave 0..15
    const int lp   = lane >> 1;         // element-pair index 0..31
    const int j    = lane & 1;          // half-row (8 dims) owner
    const int j4   = j * 4;             // dword offset within row

    const uint4* pt = reinterpret_cast<const uint4*>(wsb) + (size_t)t * NF4 * BATCH;

    #pragma unroll
    for (int sweep = 0; sweep < 2; ++sweep) {
        const int e = copy * 1024 + sweep * 512 + w * 32 + lp;

        __half2 acc0 = __float2half2_rn(0.f);
        __half2 acc1 = __float2half2_rn(0.f);
        __half2 acc2 = __float2half2_rn(0.f);
        __half2 acc3 = __float2half2_rn(0.f);

        #pragma unroll
        for (int f4 = 0; f4 < NF4; ++f4) {
            const uint4 pw = pt[(size_t)f4 * BATCH + e];   // lane-pair broadcast, 1 segment
            uint ws4[4] = {pw.x, pw.y, pw.z, pw.w};
            #pragma unroll
            for (int c = 0; c < 4; ++c) {
                const uint wrd = ws4[c];
                const uint idx = wrd & 0xffffu;
                uint v2b = (wrd & 0xffff0000u) | (wrd >> 16);   // f16 val duplicated
                const __half2 val2 = *reinterpret_cast<__half2*>(&v2b);
                const uint di = idx * ROW_DW + j4;              // 16B-aligned dword idx
                const uint4 dv = *reinterpret_cast<const uint4*>(&ldsu[di]);
                const __half2* dh = reinterpret_cast<const __half2*>(&dv);
                acc0 = __hfma2(dh[0], val2, acc0);
                acc1 = __hfma2(dh[1], val2, acc1);
                acc2 = __hfma2(dh[2], val2, acc2);
                acc3 = __hfma2(dh[3], val2, acc3);
            }
        }

        __half2 accs[4] = {acc0, acc1, acc2, acc3};
        const size_t fidx = ((size_t)(t * BATCH + e) * DIM + s * SD + j * 8);
        *reinterpret_cast<uint4*>(wsd + fidx) = *reinterpret_cast<uint4*>(accs);
    }
}

// ---- K4: final dot = (u0 + du) . (v0 + dv) ----------------------------------
__global__ __launch_bounds__(256) void k4_final(
    const int*    __restrict__ user_ids,
    const int*    __restrict__ item_ids,
    const float*  __restrict__ user_emb,
    const float*  __restrict__ item_emb,
    const ushort* __restrict__ wsd,
    float*        __restrict__ out)
{
    const int tid  = threadIdx.x;
    const int lane = tid & 63;
    const int half = lane >> 5;
    const int sl   = lane & 31;
    const int d0   = sl * 4;

    int wv = (int)((blockIdx.x * blockDim.x + tid) >> 6);
    wv = __builtin_amdgcn_readfirstlane(wv);
    const int b0 = wv * 2, b1 = b0 + 1;
    const int b  = half ? b1 : b0;

    const int uid0 = user_ids[b0], uid1 = user_ids[b1];
    const int iid0 = item_ids[b0], iid1 = item_ids[b1];
    const int ur = half ? uid1 : uid0;
    const int ir = half ? iid1 : iid0;

    const float4 u0 = *reinterpret_cast<const float4*>(user_emb + (size_t)ur * DIM + d0);
    const float4 v0 = *reinterpret_cast<const float4*>(item_emb + (size_t)ir * DIM + d0);

    const uint2 dub = *reinterpret_cast<const uint2*>(wsd + (size_t)b * DIM + d0);
    const uint2 dvb = *reinterpret_cast<const uint2*>(wsd + (size_t)(BATCH + b) * DIM + d0);
    const __half2* duh = reinterpret_cast<const __half2*>(&dub);
    const __half2* dvh = reinterpret_cast<const __half2*>(&dvb);
    const float2 du01 = __half22float2(duh[0]);
    const float2 du23 = __half22float2(duh[1]);
    const float2 dv01 = __half22float2(dvh[0]);
    const float2 dv23 = __half22float2(dvh[1]);

    float dot = (u0.x + du01.x) * (v0.x + dv01.x)
              + (u0.y + du01.y) * (v0.y + dv01.y)
              + (u0.z + du23.x) * (v0.z + dv23.x)
              + (u0.w + du23.y) * (v0.w + dv23.y);

    #pragma unroll
    for (int off = 16; off > 0; off >>= 1)
        dot += __shfl_xor(dot, off);

    if (sl == 0) out[b] = dot;
}

// ---- Fallback: R2 all-f32 single-pass (if ws too small) ---------------------
__global__ __launch_bounds__(256) void mf_dot_fallback(
    const int*   __restrict__ user_ids,
    const int*   __restrict__ item_ids,
    const int*   __restrict__ ufi,
    const float* __restrict__ ufv,
    const int*   __restrict__ ifi,
    const float* __restrict__ ifv,
    const float* __restrict__ user_emb,
    const float* __restrict__ item_emb,
    const float* __restrict__ user_feat_emb,
    const float* __restrict__ item_feat_emb,
    float*       __restrict__ out)
{
    const int tid  = threadIdx.x;
    const int lane = tid & 63;
    const int half = lane >> 5;
    const int sl   = lane & 31;
    const int d0   = sl * 4;

    int wv = (int)((blockIdx.x * blockDim.x + tid) >> 6);
    wv = __builtin_amdgcn_readfirstlane(wv);
    const int b0 = wv * 2, b1 = b0 + 1;
    const int b  = half ? b1 : b0;

    const int uid0 = user_ids[b0], uid1 = user_ids[b1];
    const int iid0 = item_ids[b0], iid1 = item_ids[b1];
    const int urow = half ? uid1 : uid0;
    const int irow = half ? iid1 : iid0;

    float4 uacc = *reinterpret_cast<const float4*>(user_emb + (size_t)urow * DIM + d0);
    float4 vacc = *reinterpret_cast<const float4*>(item_emb + (size_t)irow * DIM + d0);

    #pragma unroll 10
    for (int f = 0; f < NFEAT; ++f) {
        const int   ui0 = ufi[b0 * NFEAT + f], ui1 = ufi[b1 * NFEAT + f];
        const float uv0 = ufv[b0 * NFEAT + f], uv1 = ufv[b1 * NFEAT + f];
        const int   ii0 = ifi[b0 * NFEAT + f], ii1 = ifi[b1 * NFEAT + f];
        const float iv0 = ifv[b0 * NFEAT + f], iv1 = ifv[b1 * NFEAT + f];

        const int   ur = half ? ui1 : ui0;
        const float uw = half ? uv1 : uv0;
        const int   ir = half ? ii1 : ii0;
        const float iw = half ? iv1 : iv0;

        const float4 ue = *reinterpret_cast<const float4*>(user_feat_emb + (size_t)ur * DIM + d0);
        const float4 ie = *reinterpret_cast<const float4*>(item_feat_emb + (size_t)ir * DIM + d0);

        uacc.x = fmaf(uw, ue.x, uacc.x);
        uacc.y = fmaf(uw, ue.y, uacc.y);
        uacc.z = fmaf(uw, ue.z, uacc.z);
        uacc.w = fmaf(uw, ue.w, uacc.w);
        vacc.x = fmaf(iw, ie.x, vacc.x);
        vacc.y = fmaf(iw, ie.y, vacc.y);
        vacc.z = fmaf(iw, ie.z, vacc.z);
        vacc.w = fmaf(iw, ie.w, vacc.w);
    }

    float dot = uacc.x * vacc.x + uacc.y * vacc.y + uacc.z * vacc.z + uacc.w * vacc.w;
    #pragma unroll
    for (int off = 16; off > 0; off >>= 1)
        dot += __shfl_xor(dot, off);
    if (sl == 0) out[b] = dot;
}

extern "C" void kernel_launch(void* const* d_in, const int* in_sizes, int n_in,
                              void* d_out, int out_size, void* d_ws, size_t ws_size,
                              hipStream_t stream) {
    const int*   user_ids      = (const int*)  d_in[0];
    const int*   item_ids      = (const int*)  d_in[1];
    const int*   ufi           = (const int*)  d_in[2];
    const float* ufv           = (const float*)d_in[3];
    const int*   ifi           = (const int*)  d_in[4];
    const float* ifv           = (const float*)d_in[5];
    const float* user_emb      = (const float*)d_in[6];
    const float* item_emb      = (const float*)d_in[7];
    const float* user_feat_emb = (const float*)d_in[8];
    const float* item_feat_emb = (const float*)d_in[9];
    float* out = (float*)d_out;

    if (ws_size >= WS_NEEDED) {
        char* ws = (char*)d_ws;
        ushort* wsa = (ushort*)(ws + WSA_OFF);
        uint*   wsb = (uint*)  (ws + WSB_OFF);
        ushort* wsd = (ushort*)(ws + WSD_OFF);

        hipFuncSetAttribute((const void*)k3_delta,
                            hipFuncAttributeMaxDynamicSharedMemorySize, LDS3_BYTES);

        k1_slice_tables<<<250, 256, 0, stream>>>(user_feat_emb, item_feat_emb, wsa);
        k2_pack_transpose<<<128, 256, 0, stream>>>(ufi, ufv, ifi, ifv, wsb);
        k3_delta<<<256, 1024, LDS3_BYTES, stream>>>(wsa, wsb, wsd);
        k4_final<<<BATCH / 8, 256, 0, stream>>>(user_ids, item_ids,
                                                user_emb, item_emb, wsd, out);
    } else {
        mf_dot_fallback<<<BATCH / 8, 256, 0, stream>>>(
            user_ids, item_ids, ufi, ufv, ifi, ifv,
            user_emb, item_emb, user_feat_emb, item_feat_emb, out);
    }
}

// Round 9
// 27.948 us; speedup vs baseline: 2.2016x; 2.2016x over previous
//
#include <hip/hip_runtime.h>
#include <hip/hip_fp16.h>

#define BATCH  16384
#define NFEAT  50
#define DIM    128
#define NROWS  2000
#define TBL_HALFS (NROWS * DIM)            // 256000 halfs per table
#define WS_NEEDED (2u * TBL_HALFS * 2u)    // 1 MB

// ---- K1: convert f32 feature tables -> f16, with dim permutation -----------
// Output row layout: chunk c (16 B = 8 halfs) holds dims {c*4..c*4+3, 64+c*4..67+c*4}.
// So a quarter-wave lane q reading bytes [q*16, q*16+16) gets dims {4q..4q+3, 64+4q..+3},
// matching two contiguous f32 dwordx4 reads of the id-embedding row (offsets 0 and 256B).
__global__ __launch_bounds__(256) void k1_convert(
    const float* __restrict__ ufe,
    const float* __restrict__ ife,
    ushort*      __restrict__ wsa)
{
    const int u = blockIdx.x * 256 + threadIdx.x;   // 0..63999 chunks
    const int t   = (u >= 32000) ? 1 : 0;           // 32000 chunks per table
    const int rem = u - t * 32000;
    const int r = rem >> 4, c = rem & 15;
    const float* src = (t ? ife : ufe) + (size_t)r * DIM + c * 4;
    const float4 a = *reinterpret_cast<const float4*>(src);        // dims c*4..+3
    const float4 b = *reinterpret_cast<const float4*>(src + 64);   // dims 64+c*4..+3
    __half2 hh[4];
    hh[0] = __floats2half2_rn(a.x, a.y);
    hh[1] = __floats2half2_rn(a.z, a.w);
    hh[2] = __floats2half2_rn(b.x, b.y);
    hh[3] = __floats2half2_rn(b.z, b.w);
    *reinterpret_cast<uint4*>(wsa + ((size_t)(t * NROWS + r) * 16 + c) * 8) =
        *reinterpret_cast<uint4*>(hh);
}

// ---- Main: quarter-wave f16 gathers, 4 elements per wave --------------------
// Lanes [16e..16e+15] own element e; lane q reads 16 B (8 dims) per feature row.
// One global_load_dwordx4 = 4 feature rows (4 clusters) vs R2's 2.
// Meta (idx | f16val) staged in LDS: ds_read_b32 broadcast, no selects.
__global__ __launch_bounds__(256) void mf_dot_q(
    const int*    __restrict__ user_ids,
    const int*    __restrict__ item_ids,
    const int*    __restrict__ ufi,
    const float*  __restrict__ ufv,
    const int*    __restrict__ ifi,
    const float*  __restrict__ ifv,
    const float*  __restrict__ user_emb,
    const float*  __restrict__ item_emb,
    const ushort* __restrict__ wsa,
    float*        __restrict__ out)
{
    __shared__ uint meta[2 * 16 * NFEAT];   // 6.4 KB

    const int tid = threadIdx.x;
    const int eb  = blockIdx.x * 16;        // 16 elements per block

    // ---- stage packed (idx | f16val) meta for 16 elements, both tables ----
    #pragma unroll
    for (int rme = 0; rme < 4; ++rme) {
        const int k = rme * 256 + tid;
        if (k < 16 * NFEAT) {
            const uint  iu = (uint)ufi[(size_t)eb * NFEAT + k];
            const float vu = ufv[(size_t)eb * NFEAT + k];
            meta[k] = (iu & 0xffffu) |
                      ((uint)__half_as_ushort(__float2half_rn(vu)) << 16);
            const uint  ii = (uint)ifi[(size_t)eb * NFEAT + k];
            const float vi = ifv[(size_t)eb * NFEAT + k];
            meta[16 * NFEAT + k] = (ii & 0xffffu) |
                      ((uint)__half_as_ushort(__float2half_rn(vi)) << 16);
        }
    }
    __syncthreads();

    const int lane = tid & 63;
    const int w    = tid >> 6;
    const int q    = lane & 15;             // lane within quarter
    const int el   = w * 4 + (lane >> 4);   // local element 0..15
    const int e    = eb + el;

    // ---- id embeddings (f32, issued early; two contiguous 256B clusters) ----
    const int uid = user_ids[e];
    const int iid = item_ids[e];
    const float4 ua = *reinterpret_cast<const float4*>(user_emb + (size_t)uid * DIM + q * 4);
    const float4 ub = *reinterpret_cast<const float4*>(user_emb + (size_t)uid * DIM + 64 + q * 4);
    const float4 va = *reinterpret_cast<const float4*>(item_emb + (size_t)iid * DIM + q * 4);
    const float4 vb = *reinterpret_cast<const float4*>(item_emb + (size_t)iid * DIM + 64 + q * 4);

    const uint* __restrict__ mu = meta + el * NFEAT;
    const uint* __restrict__ mi = meta + 16 * NFEAT + el * NFEAT;
    const ushort* __restrict__ tu_base = wsa;
    const ushort* __restrict__ ti_base = wsa + TBL_HALFS;

    __half2 au0 = __float2half2_rn(0.f), au1 = au0, au2 = au0, au3 = au0;
    __half2 ai0 = au0, ai1 = au0, ai2 = au0, ai3 = au0;

    #pragma unroll 10
    for (int f = 0; f < NFEAT; ++f) {
        const uint wu = mu[f];
        const uint wi = mi[f];

        const uint4 tu = *reinterpret_cast<const uint4*>(
            tu_base + (size_t)(wu & 0xffffu) * DIM + q * 8);
        const uint4 ti = *reinterpret_cast<const uint4*>(
            ti_base + (size_t)(wi & 0xffffu) * DIM + q * 8);

        const __half2 vu2 = __half2half2(__ushort_as_half((ushort)(wu >> 16)));
        const __half2 vi2 = __half2half2(__ushort_as_half((ushort)(wi >> 16)));

        const __half2* th = reinterpret_cast<const __half2*>(&tu);
        au0 = __hfma2(th[0], vu2, au0);
        au1 = __hfma2(th[1], vu2, au1);
        au2 = __hfma2(th[2], vu2, au2);
        au3 = __hfma2(th[3], vu2, au3);
        const __half2* ih = reinterpret_cast<const __half2*>(&ti);
        ai0 = __hfma2(ih[0], vi2, ai0);
        ai1 = __hfma2(ih[1], vi2, ai1);
        ai2 = __hfma2(ih[2], vi2, ai2);
        ai3 = __hfma2(ih[3], vi2, ai3);
    }

    // du/dv chunk halfs 0..3 = dims {4q..4q+3}; halfs 4..7 = dims {64+4q..+3}
    const float2 du0 = __half22float2(au0), du1 = __half22float2(au1);
    const float2 du2 = __half22float2(au2), du3 = __half22float2(au3);
    const float2 dv0 = __half22float2(ai0), dv1 = __half22float2(ai1);
    const float2 dv2 = __half22float2(ai2), dv3 = __half22float2(ai3);

    float dot = (ua.x + du0.x) * (va.x + dv0.x)
              + (ua.y + du0.y) * (va.y + dv0.y)
              + (ua.z + du1.x) * (va.z + dv1.x)
              + (ua.w + du1.y) * (va.w + dv1.y)
              + (ub.x + du2.x) * (vb.x + dv2.x)
              + (ub.y + du2.y) * (vb.y + dv2.y)
              + (ub.z + du3.x) * (vb.z + dv3.x)
              + (ub.w + du3.y) * (vb.w + dv3.y);

    // reduce across the 16-lane quarter
    #pragma unroll
    for (int off = 8; off > 0; off >>= 1)
        dot += __shfl_xor(dot, off);

    if (q == 0) out[e] = dot;
}

// ---- Fallback: R2 all-f32 single-pass (if ws too small) ---------------------
__global__ __launch_bounds__(256) void mf_dot_fallback(
    const int*   __restrict__ user_ids,
    const int*   __restrict__ item_ids,
    const int*   __restrict__ ufi,
    const float* __restrict__ ufv,
    const int*   __restrict__ ifi,
    const float* __restrict__ ifv,
    const float* __restrict__ user_emb,
    const float* __restrict__ item_emb,
    const float* __restrict__ user_feat_emb,
    const float* __restrict__ item_feat_emb,
    float*       __restrict__ out)
{
    const int tid  = threadIdx.x;
    const int lane = tid & 63;
    const int half = lane >> 5;
    const int sl   = lane & 31;
    const int d0   = sl * 4;

    int wv = (int)((blockIdx.x * blockDim.x + tid) >> 6);
    wv = __builtin_amdgcn_readfirstlane(wv);
    const int b0 = wv * 2, b1 = b0 + 1;
    const int b  = half ? b1 : b0;

    const int uid0 = user_ids[b0], uid1 = user_ids[b1];
    const int iid0 = item_ids[b0], iid1 = item_ids[b1];
    const int urow = half ? uid1 : uid0;
    const int irow = half ? iid1 : iid0;

    float4 uacc = *reinterpret_cast<const float4*>(user_emb + (size_t)urow * DIM + d0);
    float4 vacc = *reinterpret_cast<const float4*>(item_emb + (size_t)irow * DIM + d0);

    #pragma unroll 10
    for (int f = 0; f < NFEAT; ++f) {
        const int   ui0 = ufi[b0 * NFEAT + f], ui1 = ufi[b1 * NFEAT + f];
        const float uv0 = ufv[b0 * NFEAT + f], uv1 = ufv[b1 * NFEAT + f];
        const int   ii0 = ifi[b0 * NFEAT + f], ii1 = ifi[b1 * NFEAT + f];
        const float iv0 = ifv[b0 * NFEAT + f], iv1 = ifv[b1 * NFEAT + f];

        const int   ur = half ? ui1 : ui0;
        const float uw = half ? uv1 : uv0;
        const int   ir = half ? ii1 : ii0;
        const float iw = half ? iv1 : iv0;

        const float4 ue = *reinterpret_cast<const float4*>(user_feat_emb + (size_t)ur * DIM + d0);
        const float4 ie = *reinterpret_cast<const float4*>(item_feat_emb + (size_t)ir * DIM + d0);

        uacc.x = fmaf(uw, ue.x, uacc.x);
        uacc.y = fmaf(uw, ue.y, uacc.y);
        uacc.z = fmaf(uw, ue.z, uacc.z);
        uacc.w = fmaf(uw, ue.w, uacc.w);
        vacc.x = fmaf(iw, ie.x, vacc.x);
        vacc.y = fmaf(iw, ie.y, vacc.y);
        vacc.z = fmaf(iw, ie.z, vacc.z);
        vacc.w = fmaf(iw, ie.w, vacc.w);
    }

    float dot = uacc.x * vacc.x + uacc.y * vacc.y + uacc.z * vacc.z + uacc.w * vacc.w;
    #pragma unroll
    for (int off = 16; off > 0; off >>= 1)
        dot += __shfl_xor(dot, off);
    if (sl == 0) out[b] = dot;
}

extern "C" void kernel_launch(void* const* d_in, const int* in_sizes, int n_in,
                              void* d_out, int out_size, void* d_ws, size_t ws_size,
                              hipStream_t stream) {
    const int*   user_ids      = (const int*)  d_in[0];
    const int*   item_ids      = (const int*)  d_in[1];
    const int*   ufi           = (const int*)  d_in[2];
    const float* ufv           = (const float*)d_in[3];
    const int*   ifi           = (const int*)  d_in[4];
    const float* ifv           = (const float*)d_in[5];
    const float* user_emb      = (const float*)d_in[6];
    const float* item_emb      = (const float*)d_in[7];
    const float* user_feat_emb = (const float*)d_in[8];
    const float* item_feat_emb = (const float*)d_in[9];
    float* out = (float*)d_out;

    if (ws_size >= WS_NEEDED) {
        ushort* wsa = (ushort*)d_ws;
        k1_convert<<<250, 256, 0, stream>>>(user_feat_emb, item_feat_emb, wsa);
        mf_dot_q<<<BATCH / 16, 256, 0, stream>>>(
            user_ids, item_ids, ufi, ufv, ifi, ifv,
            user_emb, item_emb, wsa, out);
    } else {
        mf_dot_fallback<<<BATCH / 8, 256, 0, stream>>>(
            user_ids, item_ids, ufi, ufv, ifi, ifv,
            user_emb, item_emb, user_feat_emb, item_feat_emb, out);
    }
}